// Round 5
// baseline (11872.902 us; speedup 1.0000x reference)
//
#include <hip/hip_runtime.h>
#include <math.h>

// Problem constants
#define B_    512
#define S_    128
#define H_    512
#define H3_   1536
#define IV_   8192
#define OUTC_ 129
#define CHUNK_ 11008       // 66048/6, divisible by 128
#define NCHUNK_ 6
#define EOS_  1

typedef __attribute__((ext_vector_type(8))) short  bf16x8;
typedef __attribute__((ext_vector_type(4))) float  f32x4;

__device__ inline unsigned short f2bf(float f) {
    union { float f; unsigned u; } x; x.f = f;
    unsigned r = x.u + 0x7FFF + ((x.u >> 16) & 1);   // RNE
    return (unsigned short)(r >> 16);
}
__device__ inline float bf2f(unsigned short b) {
    union { unsigned u; float f; } x; x.u = ((unsigned)b) << 16;
    return x.f;
}

// ---------------------------------------------------------------------------
// Generic f32 -> (hi,lo) bf16 split, optional relu first. n4 float4s.
template<bool RELU>
__global__ __launch_bounds__(256)
void split_f32(const float* __restrict__ src, unsigned short* __restrict__ hi,
               unsigned short* __restrict__ lo, int n4) {
    int i = blockIdx.x * 256 + threadIdx.x;
    if (i >= n4) return;
    float4 v = *(const float4*)&src[(size_t)i * 4];
    float a[4] = {v.x, v.y, v.z, v.w};
    size_t off = (size_t)i * 4;
    #pragma unroll
    for (int q = 0; q < 4; ++q) {
        float f = RELU ? fmaxf(a[q], 0.f) : a[q];
        unsigned short h = f2bf(f);
        hi[off + q] = h;
        lo[off + q] = f2bf(f - bf2f(h));
    }
}

// ---------------------------------------------------------------------------
// h0 gather + split
__global__ __launch_bounds__(256)
void build_h0_split(const int* __restrict__ stem, const float* __restrict__ stem_emb,
                    unsigned short* __restrict__ Hh, unsigned short* __restrict__ Hl) {
    int i = blockIdx.x * 256 + threadIdx.x;   // over B*H/4
    int b = i >> 7;
    int c = (i & 127) << 2;
    float4 v = *(const float4*)&stem_emb[(size_t)stem[b] * H_ + c];
    float a[4] = {v.x, v.y, v.z, v.w};
    size_t off = (size_t)b * H_ + c;
    #pragma unroll
    for (int q = 0; q < 4; ++q) {
        unsigned short h = f2bf(a[q]);
        Hh[off + q] = h;
        Hl[off + q] = f2bf(a[q] - bf2f(h));
    }
}

// ---------------------------------------------------------------------------
// Split-precision NT GEMM: C = (Ah+Al) @ (Wh+Wl)^T + bias, via 3 MFMA passes
// (hi*hi + lo*hi + hi*lo). A:[M,K], W:[N,K] bf16 planes. 128x128 tile, 256 thr,
// 4 waves in 2x2, each wave 64x64 = 4x4 fragments of 16x16x32 MFMA.
// OUT_MODE 0: f32 C. OUT_MODE 1: write (hi,lo) bf16 split planes.
template<int OUT_MODE, bool RELU_OUT>
__global__ __launch_bounds__(256)
void gemm_split(const unsigned short* __restrict__ Ah, const unsigned short* __restrict__ Al,
                const unsigned short* __restrict__ Wh, const unsigned short* __restrict__ Wl,
                const float* __restrict__ bias,
                float* __restrict__ Cf, unsigned short* __restrict__ Chi,
                unsigned short* __restrict__ Clo, int M, int N, int K) {
    __shared__ unsigned short As[128][72];   // pad 64->72: 2-way bank alias (free)
    __shared__ unsigned short Ws[128][72];
    const int tid = threadIdx.x;
    const int bm = blockIdx.y * 128, bn = blockIdx.x * 128;
    const int wid = tid >> 6, lane = tid & 63;
    const int wm = (wid >> 1) * 64, wn = (wid & 1) * 64;
    const int lr = lane & 15, kg = (lane >> 4) * 8;

    f32x4 acc[4][4];
    #pragma unroll
    for (int i = 0; i < 4; ++i)
        #pragma unroll
        for (int j = 0; j < 4; ++j) acc[i][j] = f32x4{0.f, 0.f, 0.f, 0.f};

    for (int ph = 0; ph < 3; ++ph) {
        const unsigned short* Ap = (ph == 1) ? Al : Ah;
        const unsigned short* Wp = (ph == 2) ? Wl : Wh;
        for (int k0 = 0; k0 < K; k0 += 64) {
            int4 av[4], wv[4];
            #pragma unroll
            for (int s = 0; s < 4; ++s) {
                int seg = s * 256 + tid;            // 1024 16B segs per tile
                int row = seg >> 3, c8 = (seg & 7) * 8;
                av[s] = *(const int4*)&Ap[(size_t)(bm + row) * K + k0 + c8];
                wv[s] = *(const int4*)&Wp[(size_t)(bn + row) * K + k0 + c8];
            }
            __syncthreads();
            #pragma unroll
            for (int s = 0; s < 4; ++s) {
                int seg = s * 256 + tid;
                int row = seg >> 3, c8 = (seg & 7) * 8;
                *(int4*)&As[row][c8] = av[s];
                *(int4*)&Ws[row][c8] = wv[s];
            }
            __syncthreads();
            #pragma unroll
            for (int ks = 0; ks < 2; ++ks) {
                bf16x8 af[4], bfr[4];
                #pragma unroll
                for (int i = 0; i < 4; ++i)
                    af[i] = *(const bf16x8*)&As[wm + i * 16 + lr][ks * 32 + kg];
                #pragma unroll
                for (int j = 0; j < 4; ++j)
                    bfr[j] = *(const bf16x8*)&Ws[wn + j * 16 + lr][ks * 32 + kg];
                #pragma unroll
                for (int i = 0; i < 4; ++i)
                    #pragma unroll
                    for (int j = 0; j < 4; ++j)
                        acc[i][j] = __builtin_amdgcn_mfma_f32_16x16x32_bf16(
                            af[i], bfr[j], acc[i][j], 0, 0, 0);
            }
        }
    }

    const int r0 = (lane >> 4) * 4, cn = lane & 15;
    #pragma unroll
    for (int i = 0; i < 4; ++i) {
        #pragma unroll
        for (int j = 0; j < 4; ++j) {
            int colg = bn + wn + j * 16 + cn;
            float bv = bias[colg];
            #pragma unroll
            for (int rg = 0; rg < 4; ++rg) {
                int rowg = bm + wm + i * 16 + r0 + rg;
                float v = acc[i][j][rg] + bv;
                if (RELU_OUT) v = fmaxf(v, 0.f);
                size_t off = (size_t)rowg * N + colg;
                if (OUT_MODE == 0) {
                    Cf[off] = v;
                } else {
                    unsigned short h = f2bf(v);
                    Chi[off] = h;
                    Clo[off] = f2bf(v - bf2f(h));
                }
            }
        }
    }
}

// ---------------------------------------------------------------------------
// Fused GRU step via split MFMA. gh = h @ W_hh^T for [BM=128 b] x [BN=32 j,
// 3 gates]; gates in epilogue; writes next-h split and relu(h) split.
__global__ __launch_bounds__(256)
void gru_step_mfma(const unsigned short* __restrict__ Hih, const unsigned short* __restrict__ Hil,
                   unsigned short* __restrict__ Hoh, unsigned short* __restrict__ Hol,
                   unsigned short* __restrict__ RHh, unsigned short* __restrict__ RHl,
                   const unsigned short* __restrict__ Wh, const unsigned short* __restrict__ Wl,
                   const float* __restrict__ GW, const float* __restrict__ b_hh,
                   const int* __restrict__ goal, int t) {
    __shared__ unsigned short As[128][72];
    __shared__ unsigned short Bs[96][72];
    const int tid = threadIdx.x;
    const int bn = blockIdx.x * 32;        // j block
    const int bm = blockIdx.y * 128;       // batch block
    const int w = tid >> 6, lane = tid & 63;
    const int lr = lane & 15, kg = (lane >> 4) * 8;

    f32x4 acc[2][6];
    #pragma unroll
    for (int i = 0; i < 2; ++i)
        #pragma unroll
        for (int f = 0; f < 6; ++f) acc[i][f] = f32x4{0.f, 0.f, 0.f, 0.f};

    for (int ph = 0; ph < 3; ++ph) {
        const unsigned short* Ap = (ph == 1) ? Hil : Hih;
        const unsigned short* Wp = (ph == 2) ? Wl : Wh;
        for (int k0 = 0; k0 < H_; k0 += 64) {
            int4 av[4], wv[3];
            #pragma unroll
            for (int s = 0; s < 4; ++s) {            // A tile 128x64
                int seg = s * 256 + tid;
                int row = seg >> 3, c8 = (seg & 7) * 8;
                av[s] = *(const int4*)&Ap[(size_t)(bm + row) * H_ + k0 + c8];
            }
            #pragma unroll
            for (int s = 0; s < 3; ++s) {            // B tile 96x64
                int seg = s * 256 + tid;
                int beta = seg >> 3, c8 = (seg & 7) * 8;
                int wrow = ((beta >> 5) << 9) + bn + (beta & 31);  // gate*512+bn+j
                wv[s] = *(const int4*)&Wp[(size_t)wrow * H_ + k0 + c8];
            }
            __syncthreads();
            #pragma unroll
            for (int s = 0; s < 4; ++s) {
                int seg = s * 256 + tid;
                *(int4*)&As[seg >> 3][(seg & 7) * 8] = av[s];
            }
            #pragma unroll
            for (int s = 0; s < 3; ++s) {
                int seg = s * 256 + tid;
                *(int4*)&Bs[seg >> 3][(seg & 7) * 8] = wv[s];
            }
            __syncthreads();
            #pragma unroll
            for (int ks = 0; ks < 2; ++ks) {
                bf16x8 af[2], bfr[6];
                #pragma unroll
                for (int i = 0; i < 2; ++i)
                    af[i] = *(const bf16x8*)&As[w * 32 + i * 16 + lr][ks * 32 + kg];
                #pragma unroll
                for (int f = 0; f < 6; ++f)
                    bfr[f] = *(const bf16x8*)&Bs[f * 16 + lr][ks * 32 + kg];
                #pragma unroll
                for (int i = 0; i < 2; ++i)
                    #pragma unroll
                    for (int f = 0; f < 6; ++f)
                        acc[i][f] = __builtin_amdgcn_mfma_f32_16x16x32_bf16(
                            af[i], bfr[f], acc[i][f], 0, 0, 0);
            }
        }
    }

    // Epilogue: gates. acc[i][f]: f = gate*2 + jf, C row=(lane>>4)*4+rg.
    const int r0 = (lane >> 4) * 4, cn = lane & 15;
    #pragma unroll
    for (int i = 0; i < 2; ++i) {
        #pragma unroll
        for (int rg = 0; rg < 4; ++rg) {
            int b = bm + w * 32 + i * 16 + r0 + rg;
            int tok = (t < S_) ? goal[(size_t)b * S_ + t] : EOS_;
            const float* gw = GW + (size_t)tok * H3_;
            #pragma unroll
            for (int jf = 0; jf < 2; ++jf) {
                int j = bn + jf * 16 + cn;
                float rp = acc[i][jf][rg]     + b_hh[j];
                float zp = acc[i][2 + jf][rg] + b_hh[512 + j];
                float hn = acc[i][4 + jf][rg] + b_hh[1024 + j];
                float r = 1.f / (1.f + expf(-(gw[j] + rp)));
                float z = 1.f / (1.f + expf(-(gw[512 + j] + zp)));
                float n = tanhf(gw[1024 + j] + r * hn);
                size_t off = (size_t)b * H_ + j;
                float hp = bf2f(Hih[off]) + bf2f(Hil[off]);
                float hv = (1.f - z) * n + z * hp;
                unsigned short hh = f2bf(hv);
                Hoh[off] = hh;
                Hol[off] = f2bf(hv - bf2f(hh));
                float rv = fmaxf(hv, 0.f);
                unsigned short rh = f2bf(rv);
                size_t roff = ((size_t)t * B_ + b) * H_ + j;
                RHh[roff] = rh;
                RHl[roff] = f2bf(rv - bf2f(rh));
            }
        }
    }
}

// ---------------------------------------------------------------------------
// logit[row] = Y2[row][:] . out_W + out_b, scattered to d_out[b][pos].
__global__ __launch_bounds__(256)
void gemv_out(const float* __restrict__ Y2, const float* __restrict__ outW,
              const float* __restrict__ outb, float* __restrict__ out, int row0) {
    int wave = threadIdx.x >> 6;
    int lane = threadIdx.x & 63;
    int row = blockIdx.x * 4 + wave;
    const float* y = Y2 + (size_t)row * H_;
    float4 v0 = *(const float4*)&y[lane * 4];
    float4 v1 = *(const float4*)&y[256 + lane * 4];
    float4 w0 = *(const float4*)&outW[lane * 4];
    float4 w1 = *(const float4*)&outW[256 + lane * 4];
    float s = v0.x * w0.x + v0.y * w0.y + v0.z * w0.z + v0.w * w0.w
            + v1.x * w1.x + v1.y * w1.y + v1.z * w1.z + v1.w * w1.w;
    #pragma unroll
    for (int off = 32; off > 0; off >>= 1) s += __shfl_down(s, off);
    if (lane == 0) {
        int r = row0 + row;
        int t = r / B_;
        int b = r - t * B_;
        int pos = (t == S_) ? 0 : t + 1;
        out[(size_t)b * OUTC_ + pos] = s + outb[0];
    }
}

// ---------------------------------------------------------------------------
__global__ __launch_bounds__(64)
void logsoftmax_rows(float* __restrict__ out) {
    int b = blockIdx.x;
    int lane = threadIdx.x;
    float* row = out + (size_t)b * OUTC_;
    float x0 = row[lane];
    float x1 = row[lane + 64];
    float x2 = (lane == 0) ? row[128] : -INFINITY;
    float m = fmaxf(fmaxf(x0, x1), x2);
    #pragma unroll
    for (int off = 32; off > 0; off >>= 1) m = fmaxf(m, __shfl_xor(m, off));
    float s = expf(x0 - m) + expf(x1 - m) + ((lane == 0) ? expf(x2 - m) : 0.f);
    #pragma unroll
    for (int off = 32; off > 0; off >>= 1) s += __shfl_xor(s, off);
    float ls = m + logf(s);
    row[lane] = x0 - ls;
    row[lane + 64] = x1 - ls;
    if (lane == 0) row[128] = x2 - ls;
}

// ---------------------------------------------------------------------------
extern "C" void kernel_launch(void* const* d_in, const int* in_sizes, int n_in,
                              void* d_out, int out_size, void* d_ws, size_t ws_size,
                              hipStream_t stream) {
    const int*   goal     = (const int*)d_in[0];
    const int*   stem     = (const int*)d_in[1];
    const float* stem_emb = (const float*)d_in[2];
    const float* word_emb = (const float*)d_in[3];
    const float* W_ih     = (const float*)d_in[4];
    const float* W_hh     = (const float*)d_in[5];
    const float* b_ih     = (const float*)d_in[6];
    const float* b_hh     = (const float*)d_in[7];
    const float* in_W     = (const float*)d_in[8];
    const float* in_b     = (const float*)d_in[9];
    const float* l0_W     = (const float*)d_in[10];
    const float* l0_b     = (const float*)d_in[11];
    const float* out_W    = (const float*)d_in[12];
    const float* out_b    = (const float*)d_in[13];
    float* out = (float*)d_out;

    // Workspace budget matters: round 1 proved >=254.3 MB exists; round 2's
    // ~280 MB layout faulted. This layout totals ~238 MB via (a) 6 MLP chunks
    // and (b) aliasing the GW-phase scratch (RWE/WIH splits) with the
    // MLP-phase scratch (Y1/Y2) — they are never live simultaneously.
    char* base = (char*)d_ws;
    auto alloc = [&](size_t bytes) -> char* {
        char* p = base; base += (bytes + 255) & ~(size_t)255; return p;
    };
    // --- persistent region ---
    float* GW            = (float*)alloc((size_t)IV_ * H3_ * 4);           // 50.3 MB
    unsigned short* RHh  = (unsigned short*)alloc((size_t)(S_ + 1) * B_ * H_ * 2); // 67.7
    unsigned short* RHl  = (unsigned short*)alloc((size_t)(S_ + 1) * B_ * H_ * 2); // 67.7
    unsigned short* WHHh = (unsigned short*)alloc((size_t)H3_ * H_ * 2);   // 1.6
    unsigned short* WHHl = (unsigned short*)alloc((size_t)H3_ * H_ * 2);   // 1.6
    unsigned short* INWh = (unsigned short*)alloc((size_t)H_ * H_ * 2);
    unsigned short* INWl = (unsigned short*)alloc((size_t)H_ * H_ * 2);
    unsigned short* L0Wh = (unsigned short*)alloc((size_t)H_ * H_ * 2);
    unsigned short* L0Wl = (unsigned short*)alloc((size_t)H_ * H_ * 2);
    unsigned short* Hh[2], *Hl[2];
    Hh[0] = (unsigned short*)alloc((size_t)B_ * H_ * 2);
    Hl[0] = (unsigned short*)alloc((size_t)B_ * H_ * 2);
    Hh[1] = (unsigned short*)alloc((size_t)B_ * H_ * 2);
    Hl[1] = (unsigned short*)alloc((size_t)B_ * H_ * 2);
    // --- union region: {RWE,WIH} (GW phase)  vs  {Y1,Y2} (MLP phase) ---
    char* uni = alloc((size_t)CHUNK_ * H_ * (2 + 2 + 4));                  // 45.1 MB
    unsigned short* RWEh = (unsigned short*)uni;                           // 8.4
    unsigned short* RWEl = RWEh + (size_t)IV_ * H_;                        // 8.4
    unsigned short* WIHh = RWEl + (size_t)IV_ * H_;                        // 1.6
    unsigned short* WIHl = WIHh + (size_t)H3_ * H_;                        // 1.6
    unsigned short* Y1h  = (unsigned short*)uni;
    unsigned short* Y1l  = Y1h + (size_t)CHUNK_ * H_;
    float* Y2            = (float*)(Y1l + (size_t)CHUNK_ * H_);

    // Splits of inputs
    split_f32<true ><<<(IV_ * H_ / 4) / 256, 256, 0, stream>>>(word_emb, RWEh, RWEl, IV_ * H_ / 4);
    split_f32<false><<<(H3_ * H_ / 4) / 256, 256, 0, stream>>>(W_ih, WIHh, WIHl, H3_ * H_ / 4);
    split_f32<false><<<(H3_ * H_ / 4) / 256, 256, 0, stream>>>(W_hh, WHHh, WHHl, H3_ * H_ / 4);
    split_f32<false><<<(H_ * H_ / 4) / 256, 256, 0, stream>>>(in_W, INWh, INWl, H_ * H_ / 4);
    split_f32<false><<<(H_ * H_ / 4) / 256, 256, 0, stream>>>(l0_W, L0Wh, L0Wl, H_ * H_ / 4);

    build_h0_split<<<(B_ * H_ / 4) / 256, 256, 0, stream>>>(stem, stem_emb, Hh[0], Hl[0]);

    // GW = relu(word_emb) @ W_ih^T + b_ih   [8192 x 1536] f32
    gemm_split<0, false><<<dim3(H3_ / 128, IV_ / 128), 256, 0, stream>>>(
        RWEh, RWEl, WIHh, WIHl, b_ih, GW, nullptr, nullptr, IV_, H3_, H_);

    // Sequential GRU (129 steps incl. EOS). Ping-pong h slots.
    for (int t = 0; t <= S_; ++t) {
        int a = t & 1, o = (t + 1) & 1;
        gru_step_mfma<<<dim3(H_ / 32, B_ / 128), 256, 0, stream>>>(
            Hh[a], Hl[a], Hh[o], Hl[o], RHh, RHl, WHHh, WHHl, GW, b_hh, goal, t);
    }

    // MLP head over 66048 relu'd states, chunked 6x.
    for (int c = 0; c < NCHUNK_; ++c) {
        size_t ro = (size_t)c * CHUNK_ * H_;
        gemm_split<1, true><<<dim3(H_ / 128, CHUNK_ / 128), 256, 0, stream>>>(
            RHh + ro, RHl + ro, INWh, INWl, in_b, nullptr, Y1h, Y1l, CHUNK_, H_, H_);
        gemm_split<0, true><<<dim3(H_ / 128, CHUNK_ / 128), 256, 0, stream>>>(
            Y1h, Y1l, L0Wh, L0Wl, l0_b, Y2, nullptr, nullptr, CHUNK_, H_, H_);
        gemv_out<<<CHUNK_ / 4, 256, 0, stream>>>(Y2, out_W, out_b, out, c * CHUNK_);
    }

    logsoftmax_rows<<<B_, 64, 0, stream>>>(out);
}